// Round 7
// baseline (1252.149 us; speedup 1.0000x reference)
//
#include <hip/hip_runtime.h>
#include <math.h>

#define Bn 64
#define Tn 512
#define Dn 256
#define Hn 256
#define Gn 1024   // 4*H

typedef _Float16 f16x2 __attribute__((ext_vector_type(2)));
typedef short bf16x8 __attribute__((ext_vector_type(8)));
typedef float f32x4 __attribute__((ext_vector_type(4)));

union U32H2 { unsigned int u; f16x2 h; };

__device__ __forceinline__ f16x2 u2h(unsigned int u) { U32H2 v; v.u = u; return v.h; }
__device__ __forceinline__ unsigned int packh2(float x, float y) {
    U32H2 v; v.h = (f16x2){(_Float16)x, (_Float16)y}; return v.u;
}

// fp32 -> bf16 round-to-nearest-even
__device__ __forceinline__ unsigned short f2bf(float x) {
    unsigned int u = __float_as_uint(x);
    u = u + 0x7FFFu + ((u >> 16) & 1u);
    return (unsigned short)(u >> 16);
}

#if __has_builtin(__builtin_amdgcn_fdot2)
__device__ __forceinline__ float fdot2f(f16x2 a, f16x2 b, float c) {
    return __builtin_amdgcn_fdot2(a, b, c, false);
}
#else
__device__ __forceinline__ float fdot2f(f16x2 a, f16x2 b, float c) {
    return fmaf((float)a[1], (float)b[1], fmaf((float)a[0], (float)b[0], c));
}
#endif

__device__ __forceinline__ float sigm(float x) {
    return __fdividef(1.0f, 1.0f + __expf(-x));
}
__device__ __forceinline__ float tanh_fast(float x) {
    float xc = fminf(fmaxf(x, -15.0f), 15.0f);
    float e = __expf(2.0f * xc);
    return 1.0f - __fdividef(2.0f, e + 1.0f);
}

// ---------------------------------------------------------------------------
// W_c[g][k] (bf16) = sum_d W_ih[g][d]*W_att[d][k];  bias_c[g] = W_ih[g]·b_att + b_ih[g] + b_hh[g]
// ---------------------------------------------------------------------------
__global__ void k_wc(const float* __restrict__ W_ih, const float* __restrict__ W_att,
                     const float* __restrict__ b_att, const float* __restrict__ b_ih,
                     const float* __restrict__ b_hh,
                     unsigned short* __restrict__ W_cb, float* __restrict__ bias_c) {
    int g = blockIdx.x;
    int k = threadIdx.x;
    __shared__ float wih_s[Dn];
    __shared__ float red[256];
    wih_s[k] = W_ih[g * Dn + k];
    __syncthreads();
    float acc = 0.0f;
    for (int d = 0; d < Dn; ++d)
        acc = fmaf(wih_s[d], W_att[d * Dn + k], acc);
    W_cb[g * Dn + k] = f2bf(acc);
    red[k] = wih_s[k] * b_att[k];
    __syncthreads();
    for (int s = 128; s > 0; s >>= 1) {
        if (k < s) red[k] += red[k + s];
        __syncthreads();
    }
    if (k == 0) bias_c[g] = red[0] + b_ih[g] + b_hh[g];
}

// ---------------------------------------------------------------------------
// vlin0[b][d] = values[b,0,:]·W_att[d,:] + b_att[d]
// ---------------------------------------------------------------------------
__global__ void k_vlin0(const float* __restrict__ values, const float* __restrict__ W_att,
                        const float* __restrict__ b_att, float* __restrict__ vlin0) {
    int b = blockIdx.x, d = threadIdx.x;
    __shared__ float v_s[Dn];
    v_s[d] = values[(size_t)b * Tn * Dn + d];
    __syncthreads();
    float acc = b_att[d];
    for (int k = 0; k < Dn; ++k)
        acc = fmaf(v_s[k], W_att[d * Dn + k], acc);
    vlin0[b * Dn + d] = acc;
}

// ---------------------------------------------------------------------------
// a_tj[b][t] = sigmoid( vlin0[b,:] · values[b,t,:] )
// ---------------------------------------------------------------------------
__global__ void k_atj(const float* __restrict__ values, const float* __restrict__ vlin0,
                      float* __restrict__ a_tj) {
    int wid = threadIdx.x >> 6, lane = threadIdx.x & 63;
    int idx = blockIdx.x * 4 + wid;            // b*T + t
    int b = idx >> 9;
    const float4* vp = (const float4*)(values + (size_t)idx * Dn);
    const float4* qp = (const float4*)(vlin0 + b * Dn);
    float4 v = vp[lane], q = qp[lane];
    float s = v.x * q.x + v.y * q.y + v.z * q.z + v.w * q.w;
    #pragma unroll
    for (int off = 32; off; off >>= 1) s += __shfl_xor(s, off);
    if (lane == 0) a_tj[idx] = 1.0f / (1.0f + expf(-s));
}

// ---------------------------------------------------------------------------
// xW = values(bf16) @ W_cb^T + bias_c ; M=32768, N=1024, K=256
// 128x128 tile, BK=32, 4 waves, mfma_f32_16x16x32_bf16
// ---------------------------------------------------------------------------
__global__ __launch_bounds__(256) void k_gemm(const float* __restrict__ A,
                                              const unsigned short* __restrict__ Bw,
                                              const float* __restrict__ bias,
                                              float* __restrict__ C) {
    __shared__ __align__(16) unsigned short As[128 * 32];
    __shared__ __align__(16) unsigned short Bs[128 * 32];
    const int tid = threadIdx.x;
    const int lane = tid & 63, wv = tid >> 6;
    const int wm = wv & 1, wn = wv >> 1;
    const int mBase = blockIdx.y * 128, nBase = blockIdx.x * 128;

    f32x4 acc[4][4];
    #pragma unroll
    for (int i = 0; i < 4; ++i)
        #pragma unroll
        for (int jj = 0; jj < 4; ++jj)
            acc[i][jj] = (f32x4){0.f, 0.f, 0.f, 0.f};

    for (int kb = 0; kb < 256; kb += 32) {
        #pragma unroll
        for (int p = 0; p < 2; ++p) {
            int idx = p * 256 + tid;
            int r = idx >> 2, c = idx & 3;
            const float* src = A + (size_t)(mBase + r) * 256 + kb + c * 8;
            float4 f0 = *(const float4*)src;
            float4 f1 = *(const float4*)(src + 4);
            bf16x8 v;
            v[0] = (short)f2bf(f0.x); v[1] = (short)f2bf(f0.y);
            v[2] = (short)f2bf(f0.z); v[3] = (short)f2bf(f0.w);
            v[4] = (short)f2bf(f1.x); v[5] = (short)f2bf(f1.y);
            v[6] = (short)f2bf(f1.z); v[7] = (short)f2bf(f1.w);
            int cs = c ^ ((r >> 1) & 3);
            *(bf16x8*)&As[r * 32 + cs * 8] = v;
        }
        #pragma unroll
        for (int p = 0; p < 2; ++p) {
            int idx = p * 256 + tid;
            int r = idx >> 2, c = idx & 3;
            bf16x8 v = *(const bf16x8*)(Bw + (size_t)(nBase + r) * 256 + kb + c * 8);
            int cs = c ^ ((r >> 1) & 3);
            *(bf16x8*)&Bs[r * 32 + cs * 8] = v;
        }
        __syncthreads();

        bf16x8 af[4], bfr[4];
        #pragma unroll
        for (int f = 0; f < 4; ++f) {
            int ra = wm * 64 + f * 16 + (lane & 15);
            int ca = (lane >> 4) ^ ((ra >> 1) & 3);
            af[f] = *(const bf16x8*)&As[ra * 32 + ca * 8];
            int rb = wn * 64 + f * 16 + (lane & 15);
            int cb = (lane >> 4) ^ ((rb >> 1) & 3);
            bfr[f] = *(const bf16x8*)&Bs[rb * 32 + cb * 8];
        }
        #pragma unroll
        for (int fm = 0; fm < 4; ++fm)
            #pragma unroll
            for (int fn = 0; fn < 4; ++fn)
                acc[fm][fn] = __builtin_amdgcn_mfma_f32_16x16x32_bf16(af[fm], bfr[fn], acc[fm][fn], 0, 0, 0);
        __syncthreads();
    }
    #pragma unroll
    for (int fm = 0; fm < 4; ++fm) {
        #pragma unroll
        for (int fn = 0; fn < 4; ++fn) {
            #pragma unroll
            for (int r = 0; r < 4; ++r) {
                int row = mBase + wm * 64 + fm * 16 + (lane >> 4) * 4 + r;
                int col = nBase + wn * 64 + fn * 16 + (lane & 15);
                C[(size_t)row * Gn + col] = acc[fm][fn][r] + bias[col];
            }
        }
    }
}

// ---------------------------------------------------------------------------
// Recurrence v7: 1 WG (1024 thr, 16 waves, 4/SIMD, 128-VGPR budget) per batch.
// Lane l: khalf=l&1, gate=(l>>1)&3, grp=l>>3; wave W. Thread owns TWO
// half-rows: rows Ra=gate*256+u1, Rb=gate*256+u2 (u1=W*8+grp, u2=u1+128),
// k-range [khalf*128, khalf*128+128): 48 pairs/row in VGPRs (96 regs),
// 16 pairs/row in 128KB stride-1 LDS (chunk-major planes).
// Phase 1 (all): dot over h_{t-1} (h reads = 2-addr broadcast, free),
//   khalf-combine via shfl_xor(1), even-khalf lanes write gate partials to
//   LDS (stride-260 -> conflict-free). Phase 2 (threads 0..255 = 1 wave/SIMD,
//   NON-redundant): gates -> nonlinearity -> h -> out + packed hbuf.
// Two lgkm-only raw barriers/step; xW/Deltas/a_tj issued at phase-1 top so
// HBM latency hides under the ~1000cy dot.
// ---------------------------------------------------------------------------
__global__ __launch_bounds__(1024, 4)
void k_rec(const float* __restrict__ xW,      // [B,T,1024] (all biases folded)
           const float* __restrict__ W_hh,    // [1024,256]
           const float* __restrict__ Deltas,  // [B,T,256]
           const float* __restrict__ a_tj,    // [B,T]
           float* __restrict__ out) {         // [B,T,256]
    extern __shared__ __align__(16) char smem[];
    uint4*    Wl4  = (uint4*)smem;                       // 8 planes x 1024 = 128KB
    float*    gLDS = (float*)(smem + 131072);            // [4][260] = 4160 B
    unsigned* hbuf = (unsigned*)(smem + 131072 + 4160);  // [2][128] u32 = 1 KB

    const int tid = threadIdx.x;
    const int b = blockIdx.x;
    const int l = tid & 63;
    const int W = tid >> 6;
    const int khalf = l & 1;
    const int gate = (l >> 1) & 3;
    const int grp = l >> 3;
    const int u1 = W * 8 + grp;          // [0,128)
    const int u2 = u1 + 128;
    const int Ra = gate * 256 + u1;
    const int Rb = gate * 256 + u2;
    const size_t xrow = (size_t)b * Tn;

    // ---- VGPR weights: 48 pairs per row (k in [khalf*128, +96)) ----
    f16x2 wa[48], wb[48];
    {
        const float4* pA = (const float4*)(W_hh + (size_t)Ra * 256) + khalf * 32;
        const float4* pB = (const float4*)(W_hh + (size_t)Rb * 256) + khalf * 32;
        #pragma unroll
        for (int q = 0; q < 24; ++q) {
            float4 v = pA[q];
            wa[2 * q + 0] = (f16x2){(_Float16)v.x, (_Float16)v.y};
            wa[2 * q + 1] = (f16x2){(_Float16)v.z, (_Float16)v.w};
            float4 w = pB[q];
            wb[2 * q + 0] = (f16x2){(_Float16)w.x, (_Float16)w.y};
            wb[2 * q + 1] = (f16x2){(_Float16)w.z, (_Float16)w.w};
        }
        // ---- LDS weights: 16 pairs per row (k in [khalf*128+96, +128)) ----
        #pragma unroll
        for (int c = 0; c < 4; ++c) {
            float4 v0 = pA[24 + 2 * c], v1 = pA[24 + 2 * c + 1];
            Wl4[c * 1024 + tid] = (uint4){ packh2(v0.x, v0.y), packh2(v0.z, v0.w),
                                           packh2(v1.x, v1.y), packh2(v1.z, v1.w) };
            float4 w0 = pB[24 + 2 * c], w1 = pB[24 + 2 * c + 1];
            Wl4[(4 + c) * 1024 + tid] = (uint4){ packh2(w0.x, w0.y), packh2(w0.z, w0.w),
                                                 packh2(w1.x, w1.y), packh2(w1.z, w1.w) };
        }
    }

    float cst = 0.0f, c0 = 0.0f, dcrun = 0.0f;

    // ---- t = 0: gates from xW only (h=0); carry c stays 0, c_0 kept ----
    if (tid < 256) {
        float gi = xW[xrow * Gn + tid];
        float gg = xW[xrow * Gn + 512 + tid];
        float go = xW[xrow * Gn + 768 + tid];
        dcrun = Deltas[xrow * Dn + tid];
        c0 = sigm(gi) * tanh_fast(gg);
        float h = sigm(go) * tanh_fast(c0);
        out[xrow * Hn + tid] = h;
        float hn = __shfl_xor(h, 1);
        if (!(tid & 1)) hbuf[tid >> 1] = packh2(h, hn);
    }
    __syncthreads();

    // ---- main loop t = 1..511 ----
    #pragma unroll 1
    for (int t = 1; t < Tn; ++t) {
        // ---- phase 1 (all threads): early loads + dot ----
        const size_t xb = (xrow + t) * Gn;
        float xw_a = xW[xb + Ra];
        float xw_b = xW[xb + Rb];
        float del = 0.0f;
        if (tid < 256) del = Deltas[(xrow + t) * Dn + tid];
        float at = a_tj[xrow + t];   // uniform -> scalar load

        const uint4* hp = (const uint4*)(hbuf + ((t - 1) & 1) * 128 + khalf * 64);
        float sa0 = 0.f, sa1 = 0.f, sb0 = 0.f, sb1 = 0.f;

        // LDS-weight section first (distinct-addr reads issued early)
        #pragma unroll
        for (int c = 0; c < 4; ++c) {
            uint4 hv = hp[12 + c];
            uint4 wA = Wl4[c * 1024 + tid];
            uint4 wB = Wl4[(4 + c) * 1024 + tid];
            sa0 = fdot2f(u2h(wA.x), u2h(hv.x), sa0);
            sa1 = fdot2f(u2h(wA.y), u2h(hv.y), sa1);
            sa0 = fdot2f(u2h(wA.z), u2h(hv.z), sa0);
            sa1 = fdot2f(u2h(wA.w), u2h(hv.w), sa1);
            sb0 = fdot2f(u2h(wB.x), u2h(hv.x), sb0);
            sb1 = fdot2f(u2h(wB.y), u2h(hv.y), sb1);
            sb0 = fdot2f(u2h(wB.z), u2h(hv.z), sb0);
            sb1 = fdot2f(u2h(wB.w), u2h(hv.w), sb1);
        }
        // VGPR-weight section
        #pragma unroll
        for (int p = 0; p < 12; ++p) {
            uint4 hv = hp[p];
            f16x2 h0 = u2h(hv.x), h1 = u2h(hv.y), h2 = u2h(hv.z), h3 = u2h(hv.w);
            sa0 = fdot2f(wa[4 * p + 0], h0, sa0);
            sa1 = fdot2f(wa[4 * p + 1], h1, sa1);
            sa0 = fdot2f(wa[4 * p + 2], h2, sa0);
            sa1 = fdot2f(wa[4 * p + 3], h3, sa1);
            sb0 = fdot2f(wb[4 * p + 0], h0, sb0);
            sb1 = fdot2f(wb[4 * p + 1], h1, sb1);
            sb0 = fdot2f(wb[4 * p + 2], h2, sb0);
            sb1 = fdot2f(wb[4 * p + 3], h3, sb1);
        }

        float Sa = sa0 + sa1;
        float Sb = sb0 + sb1;
        Sa += __shfl_xor(Sa, 1);     // combine k-halves
        Sb += __shfl_xor(Sb, 1);
        if (khalf == 0) {
            gLDS[gate * 260 + u1] = Sa + xw_a;
            gLDS[gate * 260 + u2] = Sb + xw_b;
        }
        asm volatile("s_waitcnt lgkmcnt(0)" ::: "memory");
        __builtin_amdgcn_s_barrier();
        __builtin_amdgcn_sched_barrier(0);

        // ---- phase 2 (threads 0..255, one wave per SIMD): nonlinearity ----
        if (tid < 256) {
            float gi = gLDS[tid];
            float gf = gLDS[260 + tid];
            float gg = gLDS[520 + tid];
            float go = gLDS[780 + tid];

            dcrun += del;
            float alpha = __fdividef(at, __logf(2.718281828459045f + dcrun));
            float cmix = alpha * c0 + (1.0f - alpha) * cst;
            cst = sigm(gf) * cmix + sigm(gi) * tanh_fast(gg);
            float h = sigm(go) * tanh_fast(cst);

            out[(xrow + t) * Hn + tid] = h;
            float hn = __shfl_xor(h, 1);
            if (!(tid & 1)) hbuf[(t & 1) * 128 + (tid >> 1)] = packh2(h, hn);
        }
        asm volatile("s_waitcnt lgkmcnt(0)" ::: "memory");
        __builtin_amdgcn_s_barrier();
        __builtin_amdgcn_sched_barrier(0);
    }
}

// ---------------------------------------------------------------------------
extern "C" void kernel_launch(void* const* d_in, const int* in_sizes, int n_in,
                              void* d_out, int out_size, void* d_ws, size_t ws_size,
                              hipStream_t stream) {
    const float* values = (const float*)d_in[0];
    const float* Deltas = (const float*)d_in[1];
    const float* W_att  = (const float*)d_in[2];
    const float* b_att  = (const float*)d_in[3];
    const float* W_ih   = (const float*)d_in[4];
    const float* W_hh   = (const float*)d_in[5];
    const float* b_ih   = (const float*)d_in[6];
    const float* b_hh   = (const float*)d_in[7];
    float* out = (float*)d_out;

    char* wsb = (char*)d_ws;
    float* xW            = (float*)(wsb);                       // 134,217,728 B
    unsigned short* W_cb = (unsigned short*)(wsb + 134217728);  //     524,288 B
    float* bias_c        = (float*)(wsb + 134742016);           //       4,096 B
    float* vlin0         = (float*)(wsb + 134746112);           //      65,536 B
    float* atj           = (float*)(wsb + 134811648);           //     131,072 B

    k_wc<<<1024, 256, 0, stream>>>(W_ih, W_att, b_att, b_ih, b_hh, W_cb, bias_c);
    k_vlin0<<<64, 256, 0, stream>>>(values, W_att, b_att, vlin0);
    k_atj<<<8192, 256, 0, stream>>>(values, vlin0, atj);
    k_gemm<<<dim3(8, 256), 256, 0, stream>>>(values, W_cb, bias_c, xW);
    k_rec<<<64, 1024, 131072 + 4160 + 1024, stream>>>(xW, W_hh, Deltas, atj, out);
}